// Round 9
// baseline (450.586 us; speedup 1.0000x reference)
//
#include <hip/hip_runtime.h>
#include <stdint.h>

typedef __attribute__((ext_vector_type(8))) short bhalf8;
typedef __attribute__((ext_vector_type(4))) float fx4;

__device__ __forceinline__ unsigned short f2bf(float f) {
    unsigned u = __builtin_bit_cast(unsigned, f);
    unsigned r = (u + 0x7fffu + ((u >> 16) & 1u)) >> 16;
    return (unsigned short)r;
}
__device__ __forceinline__ float bf2f(unsigned short h) {
    unsigned u = ((unsigned)h) << 16;
    return __builtin_bit_cast(float, u);
}
__device__ __forceinline__ float lrelu(float v) { return v > 0.f ? v : 0.2f * v; }

typedef __attribute__((address_space(1))) void as1_void;
typedef __attribute__((address_space(3))) void as3_void;
__device__ __forceinline__ void gl_lds16(const void* g, void* l) {
    __builtin_amdgcn_global_load_lds((as1_void*)(void*)g, (as3_void*)l, 16, 0, 0);
}

// ---------------- prep: pack (0-6911) | style (6912-7935) | rgbpart zero (7936-8703) ----------------
__global__ __launch_bounds__(256) void prep_kernel(
    const float* __restrict__ w1, const float* __restrict__ w2,
    unsigned short* __restrict__ wp1, unsigned short* __restrict__ wp2,
    const float* __restrict__ w,
    const float* __restrict__ a1w, const float* __restrict__ a1b,
    const float* __restrict__ a2w, const float* __restrict__ a2b,
    const float* __restrict__ a3w, const float* __restrict__ a3b,
    float* __restrict__ s1, float* __restrict__ s2, float* __restrict__ s3,
    float* __restrict__ rgbpart)
{
    const int bid = blockIdx.x;
    const int t = threadIdx.x;
    if (bid < 6912) {
        int tid = bid * 256 + t;
        const int N1 = 1179648, N2 = 589824;
        if (tid < N1) {
            int e = tid & 7, m = (tid >> 3) & 127, kh = (tid >> 10) & 3;
            int dx = (tid >> 12) % 3, ic = (tid / 12288) & 15;
            int dy = (tid / 196608) % 3, mblk = tid / 589824;
            int o = mblk * 128 + m, ci = ic * 32 + kh * 8 + e;
            wp1[tid] = f2bf(w1[((size_t)o * 512 + ci) * 9 + dy * 3 + dx]);
        } else if (tid < N1 + N2) {
            int t2 = tid - N1;
            int e = t2 & 7, m = (t2 >> 3) & 127, kh = (t2 >> 10) & 3;
            int dx = (t2 >> 12) % 3, ic = (t2 / 12288) & 7;
            int dy = (t2 / 98304) % 3, mblk = t2 / 294912;
            int o = mblk * 128 + m, ci = ic * 32 + kh * 8 + e;
            wp2[t2] = f2bf(w2[((size_t)o * 256 + ci) * 9 + dy * 3 + dx]);
        }
    } else if (bid < 7936) {
        int gw = (bid - 6912) * 4 + (t >> 6);   // 0..4095
        int lane = t & 63;
        int b = gw >> 10, r = gw & 1023;
        const float* arow; const float* abias; float* dst;
        if (r < 512)      { arow = a1w + (size_t)r * 512;        abias = a1b + r;       dst = s1 + b * 512 + r; }
        else if (r < 768) { int rr = r - 512; arow = a2w + (size_t)rr * 512; abias = a2b + rr; dst = s2 + b * 256 + rr; }
        else              { int rr = r - 768; arow = a3w + (size_t)rr * 512; abias = a3b + rr; dst = s3 + b * 256 + rr; }
        const float* wrow = w + b * 512;
        float acc = 0.f;
        #pragma unroll
        for (int j = 0; j < 8; ++j) {
            int c = lane + j * 64;
            acc += wrow[c] * arow[c];
        }
        #pragma unroll
        for (int off = 32; off; off >>= 1) acc += __shfl_down(acc, off, 64);
        if (lane == 0) *dst = acc + *abias;
    } else {
        int i = (bid - 7936) * 256 + t;   // 768 blocks -> 196608 floats
        rgbpart[i] = 0.f;
    }
}

// ---------------- upsample (0-2047) | demod (2048-4095) ----------------
__global__ __launch_bounds__(256) void us_demod_kernel(
    const float* __restrict__ x, const float* __restrict__ s1,
    unsigned short* __restrict__ xu,   // [4][128][128][512]
    const float* __restrict__ w1, const float* __restrict__ w2,
    const float* __restrict__ s2,
    float* __restrict__ d1, float* __restrict__ d2)
{
    const int bidg = blockIdx.x;
    const int t = threadIdx.x;
    if (bidg < 2048) {
        __shared__ float Lt[3][64][68];   // 52224 B
        const int bid = bidg;             // b(4) x k(64) x cchunk(8)
        const int cch = bid & 7, k = (bid >> 3) & 63, b = bid >> 9;
        const int c0 = cch * 64;
        {
            const int px4 = t & 15, cc4 = t >> 4;   // cc4 0..15
            #pragma unroll
            for (int r = 0; r < 3; ++r) {
                int sy = k - 1 + r; sy = sy < 0 ? 0 : (sy > 63 ? 63 : sy);
                float4 v[4];
                #pragma unroll
                for (int j = 0; j < 4; ++j)
                    v[j] = *(const float4*)&x[((size_t)(b * 512 + c0 + cc4 * 4 + j) * 64 + sy) * 64 + px4 * 4];
                #pragma unroll
                for (int o = 0; o < 4; ++o) {
                    fx4 w4;
                    w4[0] = ((const float*)&v[0])[o];
                    w4[1] = ((const float*)&v[1])[o];
                    w4[2] = ((const float*)&v[2])[o];
                    w4[3] = ((const float*)&v[3])[o];
                    *(fx4*)&Lt[r][px4 * 4 + o][cc4 * 4] = w4;
                }
            }
        }
        __syncthreads();

        const int oct = t & 7, xob = t >> 3;   // xob 0..31
        float sty[8];
        #pragma unroll
        for (int j = 0; j < 8; ++j) sty[j] = s1[b * 512 + c0 + oct * 8 + j];

        #pragma unroll
        for (int half = 0; half < 2; ++half) {     // out row 2k+half
            const int yo = 2 * k + half;
            const int rA = half ? 1 : 0, rB = rA + 1;
            const float wyA = half ? 0.75f : 0.25f, wyB = half ? 0.25f : 0.75f;
            #pragma unroll
            for (int i = 0; i < 4; ++i) {
                const int xo = xob + i * 32;
                const int kk = xo >> 1;
                int sx0, sx1; float wx0, wx1;
                if ((xo & 1) == 0) { sx0 = kk > 0 ? kk - 1 : 0; sx1 = kk; wx0 = 0.25f; wx1 = 0.75f; }
                else               { sx0 = kk; sx1 = kk < 63 ? kk + 1 : 63; wx0 = 0.75f; wx1 = 0.25f; }
                unsigned pk[4];
                #pragma unroll
                for (int h = 0; h < 2; ++h) {
                    const fx4 a0 = *(const fx4*)&Lt[rA][sx0][oct * 8 + h * 4];
                    const fx4 a1 = *(const fx4*)&Lt[rA][sx1][oct * 8 + h * 4];
                    const fx4 b0 = *(const fx4*)&Lt[rB][sx0][oct * 8 + h * 4];
                    const fx4 b1 = *(const fx4*)&Lt[rB][sx1][oct * 8 + h * 4];
                    #pragma unroll
                    for (int j2 = 0; j2 < 2; ++j2) {
                        float v0 = wyA * (wx0 * a0[j2 * 2]     + wx1 * a1[j2 * 2])
                                 + wyB * (wx0 * b0[j2 * 2]     + wx1 * b1[j2 * 2]);
                        float v1 = wyA * (wx0 * a0[j2 * 2 + 1] + wx1 * a1[j2 * 2 + 1])
                                 + wyB * (wx0 * b0[j2 * 2 + 1] + wx1 * b1[j2 * 2 + 1]);
                        v0 *= sty[h * 4 + j2 * 2];
                        v1 *= sty[h * 4 + j2 * 2 + 1];
                        pk[h * 2 + j2] = (unsigned)f2bf(v0) | ((unsigned)f2bf(v1) << 16);
                    }
                }
                *(int4*)&xu[((size_t)(b * 128 + yo) * 128 + xo) * 512 + c0 + oct * 8] =
                    make_int4(pk[0], pk[1], pk[2], pk[3]);
            }
        }
    } else {
        __shared__ float sv[512];
        __shared__ float red[4];
        int blk = bidg - 2048;            // 2048 blocks
        int conv = blk >> 10, b = (blk >> 8) & 3, o = blk & 255;
        int cin = conv ? 256 : 512;
        const float* s = conv ? (s2 + b * 256) : (s1 + b * 512);
        const float* row = (conv ? w2 : w1) + (size_t)o * cin * 9;
        for (int i = t; i < cin; i += 256) { float v = s[i]; sv[i] = v * v; }
        __syncthreads();
        float sum = 0.f;
        int n = cin * 9;
        for (int k = t; k < n; k += 256) {
            float v = row[k];
            sum += v * v * sv[k / 9];
        }
        #pragma unroll
        for (int off = 32; off; off >>= 1) sum += __shfl_down(sum, off, 64);
        if ((t & 63) == 0) red[t >> 6] = sum;
        __syncthreads();
        if (t == 0) {
            float tot = red[0] + red[1] + red[2] + red[3];
            (conv ? d2 : d1)[b * 256 + o] = rsqrtf(tot + 1e-8f);
        }
    }
}

// ---------------- 3x3 conv, implicit im2col, bf16 MFMA 16x16x32 ----------------
// r2 base structure (per-phase barriers = load-bearing for L2 weight reuse, r6).
// Changes vs r2:
//  (a) B restage split at row-death points: rows {2,3} of ic issued at start of
//      dy0; rows {0,1} of ic+1 issued at start of dy2 (rows 0,1 die after dy1's
//      barrier). Every global_load_lds now has 48 MFMAs before its draining
//      barrier — no more exposed HBM drain; barriers 4->3 per ic; B stays
//      single-buffered, LDS unchanged (80 KiB, 2 blocks/CU).
//  (b) conv1 epilogue stages the 64KB block output in LDS (dead after K-loop,
//      slot^(x&31) swizzle) and writes outmod fully coalesced (256B/pixel) —
//      kills the measured 2.2x write amplification (74MB -> ~36MB).
template<int CIN, bool IS_CONV2>
__global__ __launch_bounds__(512, 4) void conv3x3_kernel(
    const unsigned short* __restrict__ inp,
    const unsigned short* __restrict__ wpack,
    const float* __restrict__ dvec,
    const float* __restrict__ bias,
    const float* __restrict__ post,
    unsigned short* __restrict__ outmod,
    float* __restrict__ outf,
    const float* __restrict__ w3,
    float* __restrict__ rgbpart)
{
    constexpr int NIC = CIN / 32;
    __shared__ __attribute__((aligned(16))) char SMEM[81920];
    short (*Alds)[12288] = (short(*)[12288])SMEM;                    // 2 x 24576 B
    short (*Blds)[128][32] = (short(*)[128][32])(SMEM + 49152);      // 4 x 8192 B
    const int tid = threadIdx.x;
    const int lane = tid & 63;
    const int wvi = tid >> 6;         // 0..7
    const int bid = blockIdx.x;       // grid 512 = b(4) x mblk(2) x y2(64)
    const int y0 = (bid & 63) << 1;
    const int mblk = (bid >> 6) & 1;
    const int b = bid >> 7;
    const int wm = (wvi >> 2) * 64;
    const int row = (wvi >> 1) & 1;   // which of the 2 output rows
    const int wn = (wvi & 1) * 64;
    const int lhi = lane >> 4;
    const int llo = lane & 15;

    const int xg = tid >> 2, i8 = tid & 3;
    const int i8s = i8 ^ ((xg >> 1) & 3);

    fx4 acc[4][4];
    #pragma unroll
    for (int mt = 0; mt < 4; ++mt)
        #pragma unroll
        for (int nt = 0; nt < 4; ++nt) acc[mt][nt] = (fx4){0.f, 0.f, 0.f, 0.f};

    // stage 2 input rows {rp*2, rp*2+1} of channel-chunk ic into Blds
    auto stageB2 = [&](int ic, int rp) {
        #pragma unroll
        for (int rr = rp * 2; rr < rp * 2 + 2; ++rr) {
            const int yy = y0 - 1 + rr;
            char* dstB = (char*)&Blds[rr][0][0] + tid * 16;
            if ((unsigned)yy < 128u) {
                gl_lds16(inp + ((size_t)(b * 128 + yy) * 128 + xg) * CIN + ic * 32 + i8s * 8, dstB);
            } else {
                *(int4*)dstB = make_int4(0, 0, 0, 0);
            }
        }
    };
    // stage one 24.6KB A chunk (ic,dy) into Alds[buf]
    auto stageA = [&](int ic, int dy, int buf) {
        const unsigned short* asrc = wpack + ((size_t)(mblk * 3 + dy) * NIC + ic) * 12288;
        #pragma unroll
        for (int j = 0; j < 3; ++j) {
            int g = tid + j * 512;
            gl_lds16(asrc + (size_t)g * 8, (char*)&Alds[buf][0] + g * 16);
        }
    };

    // prologue: rows 0,1 of ic0 + A(0,0); rows 2,3 + A(0,1) issued inside dy0 phase
    stageB2(0, 0);
    stageA(0, 0, 0);
    __syncthreads();

    int par = 0;
    for (int ic = 0; ic < NIC; ++ic) {
        const bool lastic = (ic == NIC - 1);
        #pragma unroll
        for (int dy = 0; dy < 3; ++dy) {
            const bool last = lastic && (dy == 2);
            // ---- issue this phase's prefetches (drained by this phase's barrier,
            //      covered by this phase's 48 MFMAs) ----
            if (dy == 0) {
                stageA(ic, 1, par ^ 1);
                stageB2(ic, 1);                     // rows 2,3 of ic (needed at dy1)
            } else if (dy == 1) {
                stageA(ic, 2, par ^ 1);
            } else if (!lastic) {
                stageA(ic + 1, 0, par ^ 1);
                stageB2(ic + 1, 0);                 // rows 0,1 of ic+1 (dead since dy1 barrier)
            }
            // ---- compute 3 dx phases on Alds[par], rows row+dy ----
            const short* Ab = &Alds[par][0];
            const short* Brow = &Blds[row + dy][0][0];
            #pragma unroll
            for (int dx = 0; dx < 3; ++dx) {
                bhalf8 af[4], bfr[4];
                #pragma unroll
                for (int mt = 0; mt < 4; ++mt)
                    af[mt] = *(const bhalf8*)&Ab[dx * 4096 + (lhi * 128 + wm + mt * 16 + llo) * 8];
                #pragma unroll
                for (int nt = 0; nt < 4; ++nt) {
                    const int s = wn + nt * 16 + llo + dx;
                    if ((nt == 0 && dx == 0) || (nt == 3 && dx == 2)) {
                        // s==0 (left of image) or s==129 (right of image): zero pad
                        const bool edge = (s == 0) || (s == 129);
                        const int sp = edge ? 0 : (s - 1);
                        const int key = (sp >> 1) & 3;
                        bhalf8 v = *(const bhalf8*)&Brow[sp * 32 + ((lhi ^ key) << 3)];
                        bhalf8 z = {0, 0, 0, 0, 0, 0, 0, 0};
                        bfr[nt] = edge ? z : v;
                    } else {
                        const int sp = s - 1;
                        const int key = (sp >> 1) & 3;
                        bfr[nt] = *(const bhalf8*)&Brow[sp * 32 + ((lhi ^ key) << 3)];
                    }
                }
                __builtin_amdgcn_s_setprio(1);
                #pragma unroll
                for (int mt = 0; mt < 4; ++mt)
                    #pragma unroll
                    for (int nt = 0; nt < 4; ++nt)
                        acc[mt][nt] = __builtin_amdgcn_mfma_f32_16x16x32_bf16(
                            af[mt], bfr[nt], acc[mt][nt], 0, 0, 0);
                __builtin_amdgcn_s_setprio(0);
            }
            if (!last) __syncthreads();
            par ^= 1;
        }
    }

    // epilogue
    if constexpr (!IS_CONV2) {
        // conv1: LDS-staged coalesced write of modulated bf16 (t1).
        __syncthreads();                      // K-loop LDS dead; reuse as 64KB staging
        uint2* L = (uint2*)SMEM;              // [2][128 px][32 slots], slot = 4 ch (8B)
        #pragma unroll
        for (int mt = 0; mt < 4; ++mt) {
            const int o0 = mblk * 128 + wm + mt * 16 + lhi * 4;
            const fx4 d4 = *(const fx4*)(dvec + b * 256 + o0);
            const fx4 bb4 = *(const fx4*)(bias + o0);
            const fx4 p4 = *(const fx4*)(post + b * 256 + o0);
            const int slot = (wm >> 2) + mt * 4 + lhi;        // 0..31
            #pragma unroll
            for (int nt = 0; nt < 4; ++nt) {
                const int xo = wn + nt * 16 + llo;
                unsigned lo = 0, hi = 0;
                #pragma unroll
                for (int r = 0; r < 4; ++r) {
                    float v = acc[mt][nt][r] * d4[r] + bb4[r];
                    v = lrelu(v);
                    unsigned short ub = f2bf(v * p4[r]);
                    if (r < 2) lo |= (unsigned)ub << (16 * r);
                    else       hi |= (unsigned)ub << (16 * (r - 2));
                }
                L[((row << 7) + xo) * 32 + (slot ^ (xo & 31))] = make_uint2(lo, hi);
            }
        }
        __syncthreads();
        #pragma unroll
        for (int p = 0; p < 16; ++p) {
            const int i = p * 512 + tid;          // 0..8191
            const int pix = i >> 5;               // yl*128 + x
            const int slot = i & 31;
            const uint2 v = L[pix * 32 + (slot ^ (pix & 31))];
            const int yl = pix >> 7, xx = pix & 127;
            *(uint2*)&outmod[((size_t)(b * 128 + y0 + yl) * 128 + xx) * 256 + mblk * 128 + slot * 4] = v;
        }
    } else {
        // conv2: write h (f32, already line-coalesced) + fused to_rgb partial dots
        const int y = y0 + row;
        #pragma unroll
        for (int nt = 0; nt < 4; ++nt) {
            const int xo = wn + nt * 16 + llo;
            float pq0 = 0.f, pq1 = 0.f, pq2 = 0.f;
            #pragma unroll
            for (int mt = 0; mt < 4; ++mt) {
                const int o0 = mblk * 128 + wm + mt * 16 + lhi * 4;
                const fx4 d4 = *(const fx4*)(dvec + b * 256 + o0);
                const fx4 bb4 = *(const fx4*)(bias + o0);
                const fx4 p4 = *(const fx4*)(post + b * 256 + o0);
                const fx4 wq0 = *(const fx4*)(w3 + o0);
                const fx4 wq1 = *(const fx4*)(w3 + 256 + o0);
                const fx4 wq2 = *(const fx4*)(w3 + 512 + o0);
                #pragma unroll
                for (int r = 0; r < 4; ++r) {
                    float v = acc[mt][nt][r] * d4[r] + bb4[r];
                    v = lrelu(v);
                    outf[(((size_t)b * 256 + o0 + r) * 128 + y) * 128 + xo] = v;
                    const float hv = v * p4[r];
                    pq0 += wq0[r] * hv;
                    pq1 += wq1[r] * hv;
                    pq2 += wq2[r] * hv;
                }
            }
            pq0 += __shfl_xor(pq0, 16, 64); pq0 += __shfl_xor(pq0, 32, 64);
            pq1 += __shfl_xor(pq1, 16, 64); pq1 += __shfl_xor(pq1, 32, 64);
            pq2 += __shfl_xor(pq2, 16, 64); pq2 += __shfl_xor(pq2, 32, 64);
            if (lhi == 0) {
                float* rp = rgbpart + (size_t)b * 49152 + (size_t)y * 128 + xo;
                atomicAdd(rp, pq0);
                atomicAdd(rp + 16384, pq1);
                atomicAdd(rp + 32768, pq2);
            }
        }
    }
}

// ---------------- rgb finish: out = lrelu(partial + b3) ----------------
__global__ __launch_bounds__(256) void rgb_finish_kernel(
    const float* __restrict__ part, const float* __restrict__ b3,
    float* __restrict__ out)   // [4][3][128][128]
{
    int i = blockIdx.x * 256 + threadIdx.x;   // grid 768 -> 196608
    int q = (i >> 14) % 3;
    out[i] = lrelu(part[i] + b3[q]);
}

extern "C" void kernel_launch(void* const* d_in, const int* in_sizes, int n_in,
                              void* d_out, int out_size, void* d_ws, size_t ws_size,
                              hipStream_t stream) {
    const float* x   = (const float*)d_in[0];
    const float* w   = (const float*)d_in[1];
    const float* w1  = (const float*)d_in[2];
    const float* b1  = (const float*)d_in[3];
    const float* a1w = (const float*)d_in[4];
    const float* a1b = (const float*)d_in[5];
    const float* w2  = (const float*)d_in[6];
    const float* b2  = (const float*)d_in[7];
    const float* a2w = (const float*)d_in[8];
    const float* a2b = (const float*)d_in[9];
    const float* w3  = (const float*)d_in[10];
    const float* b3  = (const float*)d_in[11];
    const float* a3w = (const float*)d_in[12];
    const float* a3b = (const float*)d_in[13];

    char* ws = (char*)d_ws;
    unsigned short* xu  = (unsigned short*)(ws);                 // 67108864 B [4][128][128][512] bf16
    unsigned short* t1  = (unsigned short*)(ws + 67108864);      // 33554432 B [4][128][128][256] bf16
    unsigned short* wp1 = (unsigned short*)(ws + 100663296);     // 2359296 B
    unsigned short* wp2 = (unsigned short*)(ws + 103022592);     // 1179648 B
    float* s1 = (float*)(ws + 104202240);                        // 4*512
    float* s2 = (float*)(ws + 104210432);                        // 4*256
    float* s3 = (float*)(ws + 104214528);                        // 4*256
    float* d1 = (float*)(ws + 104218624);                        // 4*256
    float* d2 = (float*)(ws + 104222720);                        // 4*256
    float* rgbpart = (float*)(ws + 104226816);                   // 786432 B [4][3][128][128] f32

    float* h_out   = (float*)d_out;
    float* rgb_out = h_out + 16777216;

    prep_kernel<<<8704, 256, 0, stream>>>(w1, w2, wp1, wp2,
                                          w, a1w, a1b, a2w, a2b, a3w, a3b,
                                          s1, s2, s3, rgbpart);
    us_demod_kernel<<<4096, 256, 0, stream>>>(x, s1, xu, w1, w2, s2, d1, d2);
    conv3x3_kernel<512, false><<<512, 512, 0, stream>>>(xu, wp1, d1, b1, s2, t1, nullptr, nullptr, nullptr);
    conv3x3_kernel<256, true><<<512, 512, 0, stream>>>(t1, wp2, d2, b2, s3, nullptr, h_out, w3, rgbpart);
    rgb_finish_kernel<<<768, 256, 0, stream>>>(rgbpart, b3, rgb_out);
}